// Round 10
// baseline (1251.274 us; speedup 1.0000x reference)
//
#include <hip/hip_runtime.h>

// TrPredictor round 10 (= r9 with the MLP ping-pong overlap bug fixed):
//  - wv@wo folded in pre-kernel -> VW = N@wvo directly (no V round trip)
//  - paired-column B-frags (outputs at cols 2*l16, 2*l16+1) -> single-b32
//    LDS stores for K/Q/silu, single-u32 X RMWs, f32x2 bias loads
//  - MLP qm0/qm1 ping-pong in the DEAD K REGION, full 1152-u16 stride
//    (r9 bug: buffers at +576 overlapped rows 8-15 and the next wave)

#define SS   201
#define SP   208
#define NMT  13
#define EE   32
#define HIDN 512
#define NTRL 4
#define CWN  16
#define BB   4096
#define XST  36
#define QST  36
#define MST  72
#define VWST 228

#define X_OFF    0
#define K_OFF    14976   // K [208][36]; MLP: 4 waves x 2x[16][72] ping-pong alias
#define VWT_OFF  29952   // VW^T [32][228] (rows 0..7 also trashed by MLP alias)
#define QS_OFF   44544
#define MS_OFF   49152
#define RS_OFF   49984
#define BIAS_OFF 50816
#define SMEM_SZ  51840

#define WS_FRAG  0        // 4 layers x 72 tile slots x 1024 B (70 used/layer)
#define WS_BIAS  294912
#define WS_B1    299008
#define WS_FIN   307200
#define L2E      1.4426950408889634f

typedef unsigned short u16;
typedef unsigned int   u32;
typedef short bf16x4 __attribute__((ext_vector_type(4)));
typedef short bf16x8 __attribute__((ext_vector_type(8)));
typedef float f32x4  __attribute__((ext_vector_type(4)));
typedef float f32x2  __attribute__((ext_vector_type(2)));

#define CBAR asm volatile("" ::: "memory")

__device__ __forceinline__ f32x4 MF(bf16x8 a, bf16x8 b, f32x4 c){
  return __builtin_amdgcn_mfma_f32_16x16x32_bf16(a, b, c, 0, 0, 0);
}
__device__ __forceinline__ float bf2f(u16 u){ return __uint_as_float(((u32)u)<<16); }
__device__ __forceinline__ u16 f2bf(float f){            // exact RNE (cold paths)
  u32 u = __float_as_uint(f);
  u += 0x7fffu + ((u>>16)&1u);
  return (u16)(u>>16);
}
__device__ __forceinline__ u16 f2bf_fast(float f){
  return (u16)((__float_as_uint(f) + 0x8000u) >> 16);
}
__device__ __forceinline__ u32 pk2bf(f32x2 v){
#if defined(__has_builtin) && __has_builtin(__builtin_amdgcn_cvt_pk_bf16_f32)
  auto r = __builtin_amdgcn_cvt_pk_bf16_f32(v.x, v.y);
  u32 u; __builtin_memcpy(&u, &r, 4); return u;
#else
  return ((__float_as_uint(v.x)+0x8000u)>>16) | ((__float_as_uint(v.y)+0x8000u) & 0xffff0000u);
#endif
}
__device__ __forceinline__ f32x2 upk2(u32 d){
  return f32x2{ __uint_as_float(d<<16), __uint_as_float(d & 0xffff0000u) };
}
template<bool F32>
__device__ __forceinline__ float ldv(const void* p, int i){
  if (F32) return ((const float*)p)[i];
  return bf2f(((const u16*)p)[i]);
}
template<bool F32>
__device__ __forceinline__ u16 ldbf(const void* p, int i){
  if (F32) return f2bf(((const float*)p)[i]);
  return ((const u16*)p)[i];
}
__device__ __forceinline__ bf16x8 ld8(const u16* p){
  const bf16x4* q = (const bf16x4*)p;
  bf16x4 lo = q[0], hi = q[1];
  bf16x8 r = {lo[0],lo[1],lo[2],lo[3],hi[0],hi[1],hi[2],hi[3]};
  return r;
}

__device__ __forceinline__ int sniff_bf16(const void* tok_emb, int tid){
  int sane = 0;
  if (tid < 64){
    u16 wd = ((const u16*)tok_emb)[tid];
    int e = (wd >> 7) & 0xFF;
    sane = (e >= 100 && e <= 140) ? 1 : 0;
  }
  return (__syncthreads_count(sane) >= 52) ? 1 : 0;
}

// ===== pre-kernel 1: paired-column weight fragments (grid 288 x 64) =====
// tile map per layer (stride 72): 0,1=wq(e/o) 2,3=wk 4,5=wvo 6..37=W1(g*2+par)
// 38..69=W2(kc*2+par)   [par0=even output col 2*l16, par1=odd]
template<bool F32>
__device__ __forceinline__ void frag_body(const void* wq, const void* wk,
    const void* wv, const void* wo, const void* w1, const void* w2, void* ws)
{
  int t = blockIdx.x;
  int l = t / 72, k = t % 72;
  int lane = threadIdx.x, l16 = lane & 15, quad = lane >> 4;
  bf16x8 v;
  if (k < 2){
    #pragma unroll
    for (int j=0;j<8;j++)
      v[j] = (short)ldbf<F32>(wq, l*1024 + (quad*8+j)*32 + 2*l16 + k);
  } else if (k < 4){
    #pragma unroll
    for (int j=0;j<8;j++)
      v[j] = (short)ldbf<F32>(wk, l*1024 + (quad*8+j)*32 + 2*l16 + (k-2));
  } else if (k < 6){
    int col = 2*l16 + (k-4);
    #pragma unroll
    for (int j=0;j<8;j++){
      int a = quad*8 + j;
      float acc = 0.f;
      for (int e=0;e<EE;e++)
        acc += ldv<F32>(wv, l*1024 + a*32 + e) * ldv<F32>(wo, l*1024 + e*32 + col);
      v[j] = (short)f2bf(acc);
    }
  } else if (k < 38){
    int g = (k-6)>>1, par = (k-6)&1;
    #pragma unroll
    for (int j=0;j<8;j++)
      v[j] = (short)ldbf<F32>(w1, l*16384 + (quad*8+j)*512 + g*32 + 2*l16 + par);
  } else if (k < 70){
    int kc = (k-38)>>1, par = (k-38)&1;
    #pragma unroll
    for (int j=0;j<8;j++)
      v[j] = (short)ldbf<F32>(w2, l*16384 + (kc*32+quad*8+j)*32 + 2*l16 + par);
  } else {
    v = bf16x8{0,0,0,0,0,0,0,0};
  }
  *(bf16x8*)((char*)ws + WS_FRAG + t*1024 + lane*16) = v;
}

__global__ __launch_bounds__(64) void fmt_frags(
    const void* __restrict__ tok_emb,
    const void* __restrict__ wq, const void* __restrict__ wk,
    const void* __restrict__ wv, const void* __restrict__ wo,
    const void* __restrict__ w1, const void* __restrict__ w2,
    void* __restrict__ ws)
{
  if (sniff_bf16(tok_emb, threadIdx.x)) frag_body<false>(wq,wk,wv,wo,w1,w2,ws);
  else                                  frag_body<true >(wq,wk,wv,wo,w1,w2,ws);
}

// ===== pre-kernel 2: biases / LN / head params =====
template<bool F32>
__device__ __forceinline__ void bias_body(
    const void* bq, const void* bk, const void* bv, const void* wo, const void* bo,
    const void* ln1_g, const void* ln1_b, const void* ln2_g, const void* ln2_b,
    const void* b1, const void* b2,
    const void* lnf_g, const void* lnf_b, const void* wpen, const void* bpen,
    const void* wfan, const void* bfan, const void* wcal, const void* bcal,
    void* ws)
{
  int tid = threadIdx.x, idx = tid & 31, grp = tid >> 5;
  float* BW  = (float*)((char*)ws + WS_BIAS);
  float* BW1 = (float*)((char*)ws + WS_B1);
  float* FW  = (float*)((char*)ws + WS_FIN);
  for (int l=0;l<NTRL;l++){
    float v = 0.f;
    switch(grp){
      case 0: v = ldv<F32>(bq, l*32+idx); break;
      case 1: v = ldv<F32>(bk, l*32+idx); break;
      case 2: {
        float acc = ldv<F32>(bo, l*32+idx);
        for (int e=0;e<EE;e++) acc += ldv<F32>(bv, l*32+e) * ldv<F32>(wo, l*1024 + e*32 + idx);
        v = acc; break;
      }
      case 3: v = ldv<F32>(ln1_g, l*32+idx); break;
      case 4: v = ldv<F32>(ln1_b, l*32+idx); break;
      case 5: v = ldv<F32>(ln2_g, l*32+idx); break;
      case 6: v = ldv<F32>(ln2_b, l*32+idx); break;
      case 7: v = ldv<F32>(b2,   l*32+idx); break;
    }
    BW[l*256 + tid] = v;
  }
  for (int i=tid; i<NTRL*HIDN; i+=256) BW1[i] = ldv<F32>(b1, i);
  if (tid < 32){
    FW[tid]    = ldv<F32>(lnf_g, tid);
    FW[32+tid] = ldv<F32>(lnf_b, tid);
    FW[64+tid] = ldv<F32>(wpen, tid);
  }
  if (tid == 0) FW[96] = ldv<F32>(bpen, 0);
  if (tid < 16){ FW[97+tid] = ldv<F32>(wfan, tid); FW[113+tid] = ldv<F32>(bfan, tid); }
  if (tid < 128) FW[129+tid] = ldv<F32>(wcal, tid);
  if (tid < 8)   FW[257+tid] = ldv<F32>(bcal, tid);
}

__global__ __launch_bounds__(256) void fmt_bias(
    const void* __restrict__ tok_emb,
    const void* __restrict__ bq, const void* __restrict__ bk,
    const void* __restrict__ bv, const void* __restrict__ wo, const void* __restrict__ bo,
    const void* __restrict__ ln1_g, const void* __restrict__ ln1_b,
    const void* __restrict__ ln2_g, const void* __restrict__ ln2_b,
    const void* __restrict__ b1, const void* __restrict__ b2,
    const void* __restrict__ lnf_g, const void* __restrict__ lnf_b,
    const void* __restrict__ wpen, const void* __restrict__ bpen,
    const void* __restrict__ wfan, const void* __restrict__ bfan,
    const void* __restrict__ wcal, const void* __restrict__ bcal,
    void* __restrict__ ws)
{
  if (sniff_bf16(tok_emb, threadIdx.x))
    bias_body<false>(bq,bk,bv,wo,bo,ln1_g,ln1_b,ln2_g,ln2_b,b1,b2,
                     lnf_g,lnf_b,wpen,bpen,wfan,bfan,wcal,bcal,ws);
  else
    bias_body<true >(bq,bk,bv,wo,bo,ln1_g,ln1_b,ln2_g,ln2_b,b1,b2,
                     lnf_g,lnf_b,wpen,bpen,wfan,bfan,wcal,bcal,ws);
}

// ===== main kernel =====
__device__ __forceinline__ void ln_stats(const u16* Xb, float* MS, float* RS, int tid){
  if (tid < SP){
    const u32* row = (const u32*)(Xb + tid*XST);
    f32x2 v[16]; f32x2 s2 = {0.f,0.f};
    #pragma unroll
    for (int i=0;i<16;i++){ f32x2 p = upk2(row[i]); v[i] = p; s2 += p; }
    float m = (s2.x + s2.y) * (1.f/EE);
    f32x2 m2 = {m, m};
    f32x2 var2 = {0.f,0.f};
    #pragma unroll
    for (int i=0;i<16;i++){ f32x2 d = v[i]-m2; var2 += d*d; }
    MS[tid] = m;
    RS[tid] = rsqrtf((var2.x+var2.y)*(1.f/EE) + 1e-5f);
  }
}

__device__ __forceinline__ bf16x8 build_nfrag(const u16* Xb, const float* MS, const float* RS,
                                              int row, int quad, const f32x2* G2, const f32x2* B2){
  const u32* raw = (const u32*)(Xb + row*XST + quad*8);
  f32x2 m2 = { MS[row], MS[row] };
  f32x2 rs2 = { RS[row], RS[row] };
  u32 o[4];
  #pragma unroll
  for (int p=0;p<4;p++){
    f32x2 x = upk2(raw[p]);
    o[p] = pk2bf((x - m2) * rs2 * G2[p] + B2[p]);
  }
  bf16x8 r; __builtin_memcpy(&r, o, 16);
  return r;
}

template<bool F32>
__device__ __forceinline__ void tr_body(
    const int* seq, const int* expid,
    const void* tok_emb, const void* pos_emb,
    const void* ws, void* out, unsigned char* smem)
{
  u16*   Xb   = (u16*)(smem + X_OFF);
  u16*   Kb   = (u16*)(smem + K_OFF);
  u16*   VWTb = (u16*)(smem + VWT_OFF);
  u16*   QSb  = (u16*)(smem + QS_OFF);
  float* MS   = (float*)(smem + MS_OFF);
  float* RS   = (float*)(smem + RS_OFF);
  float* BIAS = (float*)(smem + BIAS_OFF);

  const int tid  = threadIdx.x;
  const int lane = tid & 63, w = tid >> 6;
  const int l16  = lane & 15, quad = lane >> 4;
  const int b    = blockIdx.x;
  const f32x4 Z  = {0.f,0.f,0.f,0.f};
  u16* qs  = QSb + w*576;
  // MLP ping-pong: K region is dead during Phase E. 2x[16][72] per wave,
  // FULL 1152-u16 stride (r9 bug: +576 overlapped). 4 waves x 4608 B =
  // 18432 B starting at K_OFF; spills into VWT rows 0..7, rewritten per layer.
  u16* qm0 = (u16*)(smem + K_OFF) + w*2304;
  u16* qm1 = qm0 + 1152;

  // ---- embedding + positional (pad rows zeroed) ----
  {
    const int* srow = seq + b*SS;
    for (int i = tid; i < SP*EE; i += 256){
      int s = i >> 5, e = i & 31;
      float val = 0.f;
      if (s < SS){
        int tok = srow[s];
        val = ldv<F32>(tok_emb, tok*EE + e) + ldv<F32>(pos_emb, s*EE + e);
      }
      Xb[s*XST + e] = f2bf(val);
    }
  }
  __syncthreads();

  const float qce = 0.2550546813f;  // (1/sqrt(32)) * log2(e)
  const f32x2 qce2 = {qce, qce};
  const f32x2 one2 = {1.f, 1.f};
  const f32x2 nl2e2 = {-L2E, -L2E};

  for (int l = 0; l < NTRL; ++l){
    const char* wsl = (const char*)ws + WS_FRAG + l*73728;
    // ===== Phase A =====
    bf16x8 bwq0 = *(const bf16x8*)(wsl + 0*1024 + lane*16);
    bf16x8 bwq1 = *(const bf16x8*)(wsl + 1*1024 + lane*16);
    bf16x8 bwk0 = *(const bf16x8*)(wsl + 2*1024 + lane*16);
    bf16x8 bwk1 = *(const bf16x8*)(wsl + 3*1024 + lane*16);
    bf16x8 bwv0 = *(const bf16x8*)(wsl + 4*1024 + lane*16);  // wvo even/odd
    bf16x8 bwv1 = *(const bf16x8*)(wsl + 5*1024 + lane*16);
    {
      const float* BW = (const float*)((const char*)ws + WS_BIAS) + l*256;
      BIAS[tid] = BW[tid];
    }
    // re-zero VWT pad cols 208..223 (trashed by MLP ping-pong last layer)
    for (int i = tid; i < 32*16; i += 256)
      VWTb[(i>>4)*VWST + 208 + (i&15)] = 0;
    ln_stats(Xb, MS, RS, tid);
    __syncthreads();

    // ===== Phase B: K, Q-frags, VW (paired cols, single-b32 stores) =====
    bf16x8 aq[4];
    {
      f32x2 G2[4], B2[4];
      #pragma unroll
      for (int p=0;p<4;p++){
        G2[p] = *(const f32x2*)(BIAS + 96 + quad*8 + 2*p);
        B2[p] = *(const f32x2*)(BIAS + 128 + quad*8 + 2*p);
      }
      f32x2 bqp = *(const f32x2*)(BIAS + 2*l16);
      f32x2 bkp = *(const f32x2*)(BIAS + 32 + 2*l16);
      #pragma unroll
      for (int t=0;t<4;t++){
        int m = w + 4*t;
        if (m < NMT){
          int m16 = m*16;
          bf16x8 an = build_nfrag(Xb, MS, RS, m16+l16, quad, G2, B2);
          f32x4 ck0 = MF(an, bwk0, Z), ck1 = MF(an, bwk1, Z);
          #pragma unroll
          for (int r=0;r<4;r++)
            ((u32*)(Kb + (m16+quad*4+r)*XST))[l16] = pk2bf(f32x2{ck0[r], ck1[r]} + bkp);
          f32x4 cq0 = MF(an, bwq0, Z), cq1 = MF(an, bwq1, Z);
          #pragma unroll
          for (int r=0;r<4;r++)
            ((u32*)(qs + (quad*4+r)*QST))[l16] = pk2bf((f32x2{cq0[r], cq1[r]} + bqp)*qce2);
          // VW = N @ (wv@wo) directly; scatter rows 2*l16 / 2*l16+1
          f32x4 cw0 = MF(an, bwv0, Z), cw1 = MF(an, bwv1, Z);
          #pragma unroll
          for (int r=0;r<4;r++){
            VWTb[(2*l16  )*VWST + m16 + quad*4 + r] = f2bf_fast(cw0[r]);
            VWTb[(2*l16+1)*VWST + m16 + quad*4 + r] = f2bf_fast(cw1[r]);
          }
          CBAR;
          aq[t] = ld8(qs + l16*QST + quad*8);
          CBAR;
        }
      }
    }
    __syncthreads();

    // ===== Phase C: attention =====
    {
      f32x2 OB2 = *(const f32x2*)(BIAS + 64 + 2*l16);
      #pragma unroll
      for (int t=0;t<4;t++){
        int m = w + 4*t;
        if (m < NMT){
          int m16 = m*16;
          f32x4 S[13];
          #pragma unroll
          for (int j=0;j<13;j++){
            bf16x8 kb8 = ld8(Kb + (j*16+l16)*XST + quad*8);
            S[j] = MF(aq[t], kb8, Z);
          }
          f32x2 sa = {0.f,0.f}, sb = {0.f,0.f};
          #pragma unroll
          for (int j=0;j<13;j++){
            float e0 = __builtin_amdgcn_exp2f(S[j][0]);
            float e1 = __builtin_amdgcn_exp2f(S[j][1]);
            float e2 = __builtin_amdgcn_exp2f(S[j][2]);
            float e3 = __builtin_amdgcn_exp2f(S[j][3]);
            if (j==12 && l16 >= 9){ e0=0.f; e1=0.f; e2=0.f; e3=0.f; }
            S[j] = f32x4{e0,e1,e2,e3};
            sa += f32x2{e0,e1}; sb += f32x2{e2,e3};
          }
          float sm[4] = {sa.x, sa.y, sb.x, sb.y};
          #pragma unroll
          for (int d=1; d<16; d<<=1){
            #pragma unroll
            for (int r=0;r<4;r++) sm[r] += __shfl_xor(sm[r], d);
          }
          float inv[4];
          #pragma unroll
          for (int r=0;r<4;r++) inv[r] = __builtin_amdgcn_rcpf(sm[r]);

          f32x4 o0 = Z, o1 = Z;
          #pragma unroll
          for (int c=0;c<7;c++){
            #pragma unroll
            for (int jj=0;jj<2;jj++){
              int j = 2*c + jj;
              u32 pk0 = 0, pk1 = 0;
              if (j < 13){
                pk0 = pk2bf(f32x2{S[j][0], S[j][1]});
                pk1 = pk2bf(f32x2{S[j][2], S[j][3]});
              }
              qs[(quad*4+0)*QST + jj*16 + l16] = (u16)pk0;
              qs[(quad*4+1)*QST + jj*16 + l16] = (u16)(pk0>>16);
              qs[(quad*4+2)*QST + jj*16 + l16] = (u16)pk1;
              qs[(quad*4+3)*QST + jj*16 + l16] = (u16)(pk1>>16);
            }
            CBAR;
            bf16x8 ap  = ld8(qs + l16*QST + quad*8);
            bf16x8 b0  = ld8(VWTb + (2*l16  )*VWST + c*32 + quad*8);
            bf16x8 b1f = ld8(VWTb + (2*l16+1)*VWST + c*32 + quad*8);
            o0 = MF(ap, b0, o0); o1 = MF(ap, b1f, o1);
            CBAR;
          }
          // X += inv*attn + (bv@wo+bo): single u32 RMW (paired cols)
          #pragma unroll
          for (int r=0;r<4;r++){
            u32* xp = (u32*)(Xb + (m16+quad*4+r)*XST) + l16;
            f32x2 xv = upk2(*xp);
            f32x2 iv = { inv[r], inv[r] };
            *xp = pk2bf(f32x2{o0[r], o1[r]} * iv + (xv + OB2));
          }
        }
      }
    }
    __syncthreads();

    // ===== Phase D: LN2 stats =====
    ln_stats(Xb, MS, RS, tid);
    __syncthreads();

    // ===== Phase E: MLP, ping-pong pipelined (K region scratch) =====
    {
      f32x2 G2[4], B2[4];
      #pragma unroll
      for (int p=0;p<4;p++){
        G2[p] = *(const f32x2*)(BIAS + 160 + quad*8 + 2*p);
        B2[p] = *(const f32x2*)(BIAS + 192 + quad*8 + 2*p);
      }
      bf16x8 anc[4];
      #pragma unroll
      for (int t=0;t<4;t++){
        int m = w + 4*t;
        if (m < NMT) anc[t] = build_nfrag(Xb, MS, RS, m*16+l16, quad, G2, B2);
      }
      f32x4 oacc[4][2];
      #pragma unroll
      for (int t=0;t<4;t++){ oacc[t][0] = Z; oacc[t][1] = Z; }
      const float* BW1 = (const float*)((const char*)ws + WS_B1) + l*HIDN;

      for (int c = 0; c < 8; ++c){
        const char* f1 = wsl + (6 + 4*c)*1024;
        const char* f2 = wsl + (38 + 4*c)*1024;
        bf16x8 w1e0 = *(const bf16x8*)(f1 + 0*1024 + lane*16);
        bf16x8 w1o0 = *(const bf16x8*)(f1 + 1*1024 + lane*16);
        bf16x8 w1e1 = *(const bf16x8*)(f1 + 2*1024 + lane*16);
        bf16x8 w1o1 = *(const bf16x8*)(f1 + 3*1024 + lane*16);
        bf16x8 w2e0 = *(const bf16x8*)(f2 + 0*1024 + lane*16);
        bf16x8 w2o0 = *(const bf16x8*)(f2 + 1*1024 + lane*16);
        bf16x8 w2e1 = *(const bf16x8*)(f2 + 2*1024 + lane*16);
        bf16x8 w2o1 = *(const bf16x8*)(f2 + 3*1024 + lane*16);
        int hc = c*64;
        f32x2 b1p0 = *(const f32x2*)(BW1 + hc + 2*l16);
        f32x2 b1p1 = *(const f32x2*)(BW1 + hc + 32 + 2*l16);

        auto silu_t = [&](int t, u16* dst){
          f32x4 he0 = MF(anc[t], w1e0, Z), ho0 = MF(anc[t], w1o0, Z);
          f32x4 he1 = MF(anc[t], w1e1, Z), ho1 = MF(anc[t], w1o1, Z);
          #pragma unroll
          for (int r=0;r<4;r++){
            u32* drow = (u32*)(dst + (quad*4+r)*MST);
            f32x2 z0 = f32x2{he0[r], ho0[r]} + b1p0;
            f32x2 a0 = z0 * nl2e2;
            f32x2 e0 = { __builtin_amdgcn_exp2f(a0.x), __builtin_amdgcn_exp2f(a0.y) };
            f32x2 d0 = one2 + e0;
            f32x2 rc0 = { __builtin_amdgcn_rcpf(d0.x), __builtin_amdgcn_rcpf(d0.y) };
            drow[l16] = pk2bf(z0 * rc0);
            f32x2 z1 = f32x2{he1[r], ho1[r]} + b1p1;
            f32x2 a1 = z1 * nl2e2;
            f32x2 e1 = { __builtin_amdgcn_exp2f(a1.x), __builtin_amdgcn_exp2f(a1.y) };
            f32x2 d1 = one2 + e1;
            f32x2 rc1 = { __builtin_amdgcn_rcpf(d1.x), __builtin_amdgcn_rcpf(d1.y) };
            drow[16 + l16] = pk2bf(z1 * rc1);
          }
        };

        silu_t(0, qm0);
        #pragma unroll
        for (int t=0;t<4;t++){
          int m = w + 4*t;
          if (m < NMT){
            if (t < 3 && (w + 4*(t+1)) < NMT)
              silu_t(t+1, (t&1) ? qm0 : qm1);
            u16* src = (t&1) ? qm1 : qm0;
            bf16x8 ah0 = ld8(src + l16*MST + quad*8);
            bf16x8 ah1 = ld8(src + l16*MST + 32 + quad*8);
            oacc[t][0] = MF(ah0, w2e0, oacc[t][0]);
            oacc[t][0] = MF(ah1, w2e1, oacc[t][0]);
            oacc[t][1] = MF(ah0, w2o0, oacc[t][1]);
            oacc[t][1] = MF(ah1, w2o1, oacc[t][1]);
          }
        }
      }

      f32x2 b2p = *(const f32x2*)(BIAS + 224 + 2*l16);
      #pragma unroll
      for (int t=0;t<4;t++){
        int m = w + 4*t;
        if (m < NMT){
          int m16 = m*16;
          #pragma unroll
          for (int r=0;r<4;r++){
            u32* xp = (u32*)(Xb + (m16+quad*4+r)*XST) + l16;
            f32x2 xv = upk2(*xp);
            *xp = pk2bf(f32x2{oacc[t][0][r], oacc[t][1][r]} + (xv + b2p));
          }
        }
      }
    }
    __syncthreads();
  }

  // ===== final head =====
  const float* FW = (const float*)((const char*)ws + WS_FIN);
  if (tid < 32){
    BIAS[tid]    = FW[tid];
    BIAS[32+tid] = FW[32+tid];
    BIAS[64+tid] = FW[64+tid];
  }
  __syncthreads();
  float part = 0.f;
  if (tid < SS){
    const u32* row = (const u32*)(Xb + tid*XST);
    f32x2 v[16]; f32x2 s2 = {0.f,0.f};
    #pragma unroll
    for (int i=0;i<16;i++){ f32x2 p = upk2(row[i]); v[i] = p; s2 += p; }
    float m = (s2.x+s2.y) * (1.f/EE);
    f32x2 m2 = {m,m};
    f32x2 var2 = {0.f,0.f};
    #pragma unroll
    for (int i=0;i<16;i++){ f32x2 d = v[i]-m2; var2 += d*d; }
    float rs = rsqrtf((var2.x+var2.y)*(1.f/EE) + 1e-5f);
    f32x2 rs2 = {rs, rs};
    f32x2 dot2 = {0.f,0.f};
    #pragma unroll
    for (int i=0;i<16;i++){
      f32x2 g  = *(const f32x2*)(BIAS + 2*i);
      f32x2 bb = *(const f32x2*)(BIAS + 32 + 2*i);
      f32x2 wp = *(const f32x2*)(BIAS + 64 + 2*i);
      dot2 += ((v[i]-m2)*rs2*g + bb) * wp;
    }
    part = dot2.x + dot2.y + FW[96];
  }
  #pragma unroll
  for (int off=32; off; off>>=1) part += __shfl_xor(part, off);
  float* REDF = (float*)(smem + QS_OFF);
  __syncthreads();
  if (lane == 0) REDF[w] = part;
  __syncthreads();
  if (tid == 0){
    float u = REDF[0] + REDF[1] + REDF[2] + REDF[3];
    int ex = expid[b];
    float corr = FW[257+ex];
    #pragma unroll
    for (int c = 0; c < CWN; ++c){
      float pre = u * FW[97+c] + FW[113+c];
      pre = pre > 0.f ? pre : (__expf(pre) - 1.f);
      corr += pre * FW[129 + ex*CWN + c];
    }
    float res = corr + u;
    if (F32) ((float*)out)[b] = res;
    else     ((u16*)out)[b]  = f2bf(res);
  }
}

__global__ __launch_bounds__(256, 3) void tr_kernel(
    const int* __restrict__ seq, const int* __restrict__ expid,
    const void* __restrict__ tok_emb, const void* __restrict__ pos_emb,
    const void* __restrict__ ws, void* __restrict__ out)
{
  __shared__ __align__(16) unsigned char smem[SMEM_SZ];
  if (sniff_bf16(tok_emb, threadIdx.x))
    tr_body<false>(seq, expid, tok_emb, pos_emb, ws, out, smem);
  else
    tr_body<true >(seq, expid, tok_emb, pos_emb, ws, out, smem);
}

extern "C" void kernel_launch(void* const* d_in, const int* in_sizes, int n_in,
                              void* d_out, int out_size, void* d_ws, size_t ws_size,
                              hipStream_t stream)
{
  (void)in_sizes; (void)n_in; (void)ws_size; (void)out_size;
  const void* tok_emb = d_in[2];
  fmt_frags<<<dim3(288), dim3(64), 0, stream>>>(
      tok_emb, d_in[6], d_in[7], d_in[8], d_in[12], d_in[16], d_in[18], d_ws);
  fmt_bias<<<dim3(1), dim3(256), 0, stream>>>(
      tok_emb, d_in[9], d_in[10], d_in[11], d_in[12], d_in[13],
      d_in[4], d_in[5], d_in[14], d_in[15], d_in[17], d_in[19],
      d_in[20], d_in[21], d_in[22], d_in[23],
      d_in[24], d_in[25], d_in[26], d_in[27], d_ws);
  tr_kernel<<<dim3(BB), dim3(256), 0, stream>>>(
      (const int*)d_in[0], (const int*)d_in[1], tok_emb, d_in[3], d_ws, d_out);
}

// Round 11
// 996.194 us; speedup vs baseline: 1.2561x; 1.2561x over previous
//
#include <hip/hip_runtime.h>

// TrPredictor round 11 = r8 (1,002 us, verified) + wv@wo fold ONLY.
// r10 post-mortem: Phase-E pipelining caused scratch spills (WRITE_SIZE
// 11->490 MB); reverted. wvo fold removes 2 MFMAs + one LDS round trip per
// Phase-B tile with NO added live registers.

#define SS   201
#define SP   208
#define NMT  13
#define EE   32
#define HIDN 512
#define NTRL 4
#define CWN  16
#define BB   4096
#define XST  36
#define QST  36
#define MST  72
#define VWST 228

#define X_OFF    0
#define K_OFF    14976
#define VWT_OFF  29952   // VW^T [32][228]; MLP: 4x[16][72] scratch aliases (r8 layout)
#define QS_OFF   44544
#define MS_OFF   49152
#define RS_OFF   49984
#define BIAS_OFF 50816
#define SMEM_SZ  51840

#define WS_FRAG  0        // 288 tiles x 1024 B; per layer: 0,1=q 2,3=k 4,5=wvo 6,7=unused
#define WS_BIAS  294912
#define WS_B1    299008
#define WS_FIN   307200
#define L2E      1.4426950408889634f

typedef unsigned short u16;
typedef unsigned int   u32;
typedef short bf16x4 __attribute__((ext_vector_type(4)));
typedef short bf16x8 __attribute__((ext_vector_type(8)));
typedef float f32x4  __attribute__((ext_vector_type(4)));
typedef float f32x2  __attribute__((ext_vector_type(2)));

#define CBAR asm volatile("" ::: "memory")

__device__ __forceinline__ f32x4 MF(bf16x8 a, bf16x8 b, f32x4 c){
  return __builtin_amdgcn_mfma_f32_16x16x32_bf16(a, b, c, 0, 0, 0);
}
__device__ __forceinline__ float bf2f(u16 u){ return __uint_as_float(((u32)u)<<16); }
__device__ __forceinline__ u16 f2bf(float f){            // exact RNE (cold paths)
  u32 u = __float_as_uint(f);
  u += 0x7fffu + ((u>>16)&1u);
  return (u16)(u>>16);
}
__device__ __forceinline__ u16 f2bf_fast(float f){
  return (u16)((__float_as_uint(f) + 0x8000u) >> 16);
}
__device__ __forceinline__ u32 pk2bf(f32x2 v){
#if defined(__has_builtin) && __has_builtin(__builtin_amdgcn_cvt_pk_bf16_f32)
  auto r = __builtin_amdgcn_cvt_pk_bf16_f32(v.x, v.y);
  u32 u; __builtin_memcpy(&u, &r, 4); return u;
#else
  return ((__float_as_uint(v.x)+0x8000u)>>16) | ((__float_as_uint(v.y)+0x8000u) & 0xffff0000u);
#endif
}
__device__ __forceinline__ f32x2 upk2(u32 d){
  return f32x2{ __uint_as_float(d<<16), __uint_as_float(d & 0xffff0000u) };
}
template<bool F32>
__device__ __forceinline__ float ldv(const void* p, int i){
  if (F32) return ((const float*)p)[i];
  return bf2f(((const u16*)p)[i]);
}
template<bool F32>
__device__ __forceinline__ u16 ldbf(const void* p, int i){
  if (F32) return f2bf(((const float*)p)[i]);
  return ((const u16*)p)[i];
}
__device__ __forceinline__ bf16x8 ld8(const u16* p){
  const bf16x4* q = (const bf16x4*)p;
  bf16x4 lo = q[0], hi = q[1];
  bf16x8 r = {lo[0],lo[1],lo[2],lo[3],hi[0],hi[1],hi[2],hi[3]};
  return r;
}

__device__ __forceinline__ int sniff_bf16(const void* tok_emb, int tid){
  int sane = 0;
  if (tid < 64){
    u16 wd = ((const u16*)tok_emb)[tid];
    int e = (wd >> 7) & 0xFF;
    sane = (e >= 100 && e <= 140) ? 1 : 0;
  }
  return (__syncthreads_count(sane) >= 52) ? 1 : 0;
}

// ===== pre-kernel 1: weight fragments (grid 288 x 64), r8 layout =====
template<bool F32>
__device__ __forceinline__ void frag_body(const void* wq, const void* wk,
    const void* wv, const void* wo, const void* w1, const void* w2, void* ws)
{
  int t = blockIdx.x;
  int l = t / 72, k = t % 72;
  int lane = threadIdx.x, l16 = lane & 15, quad = lane >> 4;
  bf16x8 v;
  if (k < 8){
    int mat = k >> 1, half = k & 1;
    if (mat == 2){
      // wvo = wv @ wo  (f32 accumulate, single bf16 rounding)
      int col = half*16 + l16;
      #pragma unroll
      for (int j=0;j<8;j++){
        int a = quad*8 + j;
        float acc = 0.f;
        for (int e=0;e<EE;e++)
          acc += ldv<F32>(wv, l*1024 + a*32 + e) * ldv<F32>(wo, l*1024 + e*32 + col);
        v[j] = (short)f2bf(acc);
      }
    } else {
      const void* src = (mat==0)? wq : (mat==1)? wk : wo;
      #pragma unroll
      for (int j=0;j<8;j++)
        v[j] = (short)ldbf<F32>(src, l*1024 + (quad*8+j)*32 + half*16 + l16);
    }
  } else if (k < 40){
    int nt = k - 8;
    #pragma unroll
    for (int j=0;j<8;j++)
      v[j] = (short)ldbf<F32>(w1, l*16384 + (quad*8+j)*512 + nt*16 + l16);
  } else {
    int kc = (k-40)>>1, nh = (k-40)&1;
    #pragma unroll
    for (int j=0;j<8;j++)
      v[j] = (short)ldbf<F32>(w2, l*16384 + (kc*32+quad*8+j)*32 + nh*16 + l16);
  }
  *(bf16x8*)((char*)ws + WS_FRAG + t*1024 + lane*16) = v;
}

__global__ __launch_bounds__(64) void fmt_frags(
    const void* __restrict__ tok_emb,
    const void* __restrict__ wq, const void* __restrict__ wk,
    const void* __restrict__ wv, const void* __restrict__ wo,
    const void* __restrict__ w1, const void* __restrict__ w2,
    void* __restrict__ ws)
{
  if (sniff_bf16(tok_emb, threadIdx.x)) frag_body<false>(wq,wk,wv,wo,w1,w2,ws);
  else                                  frag_body<true >(wq,wk,wv,wo,w1,w2,ws);
}

// ===== pre-kernel 2: biases / LN / head params =====
template<bool F32>
__device__ __forceinline__ void bias_body(
    const void* bq, const void* bk, const void* bv, const void* wo, const void* bo,
    const void* ln1_g, const void* ln1_b, const void* ln2_g, const void* ln2_b,
    const void* b1, const void* b2,
    const void* lnf_g, const void* lnf_b, const void* wpen, const void* bpen,
    const void* wfan, const void* bfan, const void* wcal, const void* bcal,
    void* ws)
{
  int tid = threadIdx.x, idx = tid & 31, grp = tid >> 5;
  float* BW  = (float*)((char*)ws + WS_BIAS);
  float* BW1 = (float*)((char*)ws + WS_B1);
  float* FW  = (float*)((char*)ws + WS_FIN);
  for (int l=0;l<NTRL;l++){
    float v = 0.f;
    switch(grp){
      case 0: v = ldv<F32>(bq, l*32+idx); break;
      case 1: v = ldv<F32>(bk, l*32+idx); break;
      case 2: {
        float acc = ldv<F32>(bo, l*32+idx);
        for (int e=0;e<EE;e++) acc += ldv<F32>(bv, l*32+e) * ldv<F32>(wo, l*1024 + e*32 + idx);
        v = acc; break;
      }
      case 3: v = ldv<F32>(ln1_g, l*32+idx); break;
      case 4: v = ldv<F32>(ln1_b, l*32+idx); break;
      case 5: v = ldv<F32>(ln2_g, l*32+idx); break;
      case 6: v = ldv<F32>(ln2_b, l*32+idx); break;
      case 7: v = ldv<F32>(b2,   l*32+idx); break;
    }
    BW[l*256 + tid] = v;
  }
  for (int i=tid; i<NTRL*HIDN; i+=256) BW1[i] = ldv<F32>(b1, i);
  if (tid < 32){
    FW[tid]    = ldv<F32>(lnf_g, tid);
    FW[32+tid] = ldv<F32>(lnf_b, tid);
    FW[64+tid] = ldv<F32>(wpen, tid);
  }
  if (tid == 0) FW[96] = ldv<F32>(bpen, 0);
  if (tid < 16){ FW[97+tid] = ldv<F32>(wfan, tid); FW[113+tid] = ldv<F32>(bfan, tid); }
  if (tid < 128) FW[129+tid] = ldv<F32>(wcal, tid);
  if (tid < 8)   FW[257+tid] = ldv<F32>(bcal, tid);
}

__global__ __launch_bounds__(256) void fmt_bias(
    const void* __restrict__ tok_emb,
    const void* __restrict__ bq, const void* __restrict__ bk,
    const void* __restrict__ bv, const void* __restrict__ wo, const void* __restrict__ bo,
    const void* __restrict__ ln1_g, const void* __restrict__ ln1_b,
    const void* __restrict__ ln2_g, const void* __restrict__ ln2_b,
    const void* __restrict__ b1, const void* __restrict__ b2,
    const void* __restrict__ lnf_g, const void* __restrict__ lnf_b,
    const void* __restrict__ wpen, const void* __restrict__ bpen,
    const void* __restrict__ wfan, const void* __restrict__ bfan,
    const void* __restrict__ wcal, const void* __restrict__ bcal,
    void* __restrict__ ws)
{
  if (sniff_bf16(tok_emb, threadIdx.x))
    bias_body<false>(bq,bk,bv,wo,bo,ln1_g,ln1_b,ln2_g,ln2_b,b1,b2,
                     lnf_g,lnf_b,wpen,bpen,wfan,bfan,wcal,bcal,ws);
  else
    bias_body<true >(bq,bk,bv,wo,bo,ln1_g,ln1_b,ln2_g,ln2_b,b1,b2,
                     lnf_g,lnf_b,wpen,bpen,wfan,bfan,wcal,bcal,ws);
}

// ===== main kernel =====
__device__ __forceinline__ void ln_stats(const u16* Xb, float* MS, float* RS, int tid){
  if (tid < SP){
    const u32* row = (const u32*)(Xb + tid*XST);
    f32x2 v[16]; f32x2 s2 = {0.f,0.f};
    #pragma unroll
    for (int i=0;i<16;i++){ f32x2 p = upk2(row[i]); v[i] = p; s2 += p; }
    float m = (s2.x + s2.y) * (1.f/EE);
    f32x2 m2 = {m, m};
    f32x2 var2 = {0.f,0.f};
    #pragma unroll
    for (int i=0;i<16;i++){ f32x2 d = v[i]-m2; var2 += d*d; }
    MS[tid] = m;
    RS[tid] = rsqrtf((var2.x+var2.y)*(1.f/EE) + 1e-5f);
  }
}

__device__ __forceinline__ bf16x8 build_nfrag(const u16* Xb, const float* MS, const float* RS,
                                              int row, int quad, const f32x2* G2, const f32x2* B2){
  const u32* raw = (const u32*)(Xb + row*XST + quad*8);
  f32x2 m2 = { MS[row], MS[row] };
  f32x2 rs2 = { RS[row], RS[row] };
  u32 o[4];
  #pragma unroll
  for (int p=0;p<4;p++){
    f32x2 x = upk2(raw[p]);
    o[p] = pk2bf((x - m2) * rs2 * G2[p] + B2[p]);
  }
  bf16x8 r; __builtin_memcpy(&r, o, 16);
  return r;
}

template<bool F32>
__device__ __forceinline__ void tr_body(
    const int* seq, const int* expid,
    const void* tok_emb, const void* pos_emb,
    const void* ws, void* out, unsigned char* smem)
{
  u16*   Xb   = (u16*)(smem + X_OFF);
  u16*   Kb   = (u16*)(smem + K_OFF);
  u16*   VWTb = (u16*)(smem + VWT_OFF);
  u16*   QSb  = (u16*)(smem + QS_OFF);
  float* MS   = (float*)(smem + MS_OFF);
  float* RS   = (float*)(smem + RS_OFF);
  float* BIAS = (float*)(smem + BIAS_OFF);

  const int tid  = threadIdx.x;
  const int lane = tid & 63, w = tid >> 6;
  const int l16  = lane & 15, quad = lane >> 4;
  const int b    = blockIdx.x;
  const f32x4 Z  = {0.f,0.f,0.f,0.f};
  u16* qs = QSb + w*576;
  u16* qm = (u16*)(smem + VWT_OFF) + w*1152;   // r8 MLP scratch layout

  // ---- embedding + positional (pad rows zeroed) ----
  {
    const int* srow = seq + b*SS;
    for (int i = tid; i < SP*EE; i += 256){
      int s = i >> 5, e = i & 31;
      float val = 0.f;
      if (s < SS){
        int tok = srow[s];
        val = ldv<F32>(tok_emb, tok*EE + e) + ldv<F32>(pos_emb, s*EE + e);
      }
      Xb[s*XST + e] = f2bf(val);
    }
  }
  __syncthreads();

  const float qce = 0.2550546813f;  // (1/sqrt(32)) * log2(e)
  const f32x2 qce2 = {qce, qce};
  const f32x2 one2 = {1.f, 1.f};
  const f32x2 nl2e2 = {-L2E, -L2E};

  for (int l = 0; l < NTRL; ++l){
    const char* wsl = (const char*)ws + WS_FRAG + l*73728;
    // ===== Phase A =====
    bf16x8 bwq0 = *(const bf16x8*)(wsl + 0*1024 + lane*16);
    bf16x8 bwq1 = *(const bf16x8*)(wsl + 1*1024 + lane*16);
    bf16x8 bwk0 = *(const bf16x8*)(wsl + 2*1024 + lane*16);
    bf16x8 bwk1 = *(const bf16x8*)(wsl + 3*1024 + lane*16);
    bf16x8 bwv0 = *(const bf16x8*)(wsl + 4*1024 + lane*16);  // wvo halves
    bf16x8 bwv1 = *(const bf16x8*)(wsl + 5*1024 + lane*16);
    {
      const float* BW = (const float*)((const char*)ws + WS_BIAS) + l*256;
      BIAS[tid] = BW[tid];
    }
    for (int i = tid; i < 32*16; i += 256)
      VWTb[(i>>4)*VWST + 208 + (i&15)] = 0;
    ln_stats(Xb, MS, RS, tid);
    __syncthreads();

    // ===== Phase B: K, VW (= N@wvo), Q-fragments =====
    bf16x8 aq[4];
    {
      f32x2 G2[4], B2[4];
      #pragma unroll
      for (int p=0;p<4;p++){
        G2[p] = f32x2{BIAS[96+quad*8+2*p], BIAS[96+quad*8+2*p+1]};
        B2[p] = f32x2{BIAS[128+quad*8+2*p], BIAS[128+quad*8+2*p+1]};
      }
      f32x2 bqb2 = {BIAS[l16],    BIAS[16+l16]};
      f32x2 bkb2 = {BIAS[32+l16], BIAS[48+l16]};
      #pragma unroll
      for (int t=0;t<4;t++){
        int m = w + 4*t;
        if (m < NMT){
          int m16 = m*16;
          bf16x8 an = build_nfrag(Xb, MS, RS, m16+l16, quad, G2, B2);
          f32x4 ck0 = MF(an, bwk0, Z), ck1 = MF(an, bwk1, Z);
          #pragma unroll
          for (int r=0;r<4;r++){
            int row = m16 + quad*4 + r;
            u32 pk = pk2bf(f32x2{ck0[r], ck1[r]} + bkb2);
            Kb[row*XST + l16]      = (u16)pk;
            Kb[row*XST + 16 + l16] = (u16)(pk>>16);
          }
          // VW = N @ wvo directly (fold removes V round trip)
          f32x4 cw0 = MF(an, bwv0, Z), cw1 = MF(an, bwv1, Z);
          #pragma unroll
          for (int r=0;r<4;r++){
            u32 pk = pk2bf(f32x2{cw0[r], cw1[r]});
            VWTb[l16*VWST      + m16 + quad*4 + r] = (u16)pk;
            VWTb[(16+l16)*VWST + m16 + quad*4 + r] = (u16)(pk>>16);
          }
          // Q (scaled) -> scratch -> A-frag
          f32x4 cq0 = MF(an, bwq0, Z), cq1 = MF(an, bwq1, Z);
          #pragma unroll
          for (int r=0;r<4;r++){
            u32 pk = pk2bf((f32x2{cq0[r], cq1[r]} + bqb2) * qce2);
            qs[(quad*4+r)*QST + l16]      = (u16)pk;
            qs[(quad*4+r)*QST + 16 + l16] = (u16)(pk>>16);
          }
          CBAR;
          aq[t] = ld8(qs + l16*QST + quad*8);
          CBAR;
        }
      }
    }
    __syncthreads();

    // ===== Phase C: attention =====
    {
      f32x2 OB2 = {BIAS[64+l16], BIAS[80+l16]};
      #pragma unroll
      for (int t=0;t<4;t++){
        int m = w + 4*t;
        if (m < NMT){
          int m16 = m*16;
          f32x4 S[13];
          #pragma unroll
          for (int j=0;j<13;j++){
            bf16x8 kb8 = ld8(Kb + (j*16+l16)*XST + quad*8);
            S[j] = MF(aq[t], kb8, Z);
          }
          f32x2 sa = {0.f,0.f}, sb = {0.f,0.f};
          #pragma unroll
          for (int j=0;j<13;j++){
            float e0 = __builtin_amdgcn_exp2f(S[j][0]);
            float e1 = __builtin_amdgcn_exp2f(S[j][1]);
            float e2 = __builtin_amdgcn_exp2f(S[j][2]);
            float e3 = __builtin_amdgcn_exp2f(S[j][3]);
            if (j==12 && l16 >= 9){ e0=0.f; e1=0.f; e2=0.f; e3=0.f; }
            S[j] = f32x4{e0,e1,e2,e3};
            sa += f32x2{e0,e1}; sb += f32x2{e2,e3};
          }
          float sm[4] = {sa.x, sa.y, sb.x, sb.y};
          #pragma unroll
          for (int d=1; d<16; d<<=1){
            #pragma unroll
            for (int r=0;r<4;r++) sm[r] += __shfl_xor(sm[r], d);
          }
          float inv[4];
          #pragma unroll
          for (int r=0;r<4;r++) inv[r] = __builtin_amdgcn_rcpf(sm[r]);

          f32x4 o0 = Z, o1 = Z;
          #pragma unroll
          for (int c=0;c<7;c++){
            #pragma unroll
            for (int jj=0;jj<2;jj++){
              int j = 2*c + jj;
              u32 pk0 = 0, pk1 = 0;
              if (j < 13){
                pk0 = pk2bf(f32x2{S[j][0], S[j][1]});
                pk1 = pk2bf(f32x2{S[j][2], S[j][3]});
              }
              qs[(quad*4+0)*QST + jj*16 + l16] = (u16)pk0;
              qs[(quad*4+1)*QST + jj*16 + l16] = (u16)(pk0>>16);
              qs[(quad*4+2)*QST + jj*16 + l16] = (u16)pk1;
              qs[(quad*4+3)*QST + jj*16 + l16] = (u16)(pk1>>16);
            }
            CBAR;
            bf16x8 ap  = ld8(qs + l16*QST + quad*8);
            bf16x8 b0  = ld8(VWTb + l16*VWST      + c*32 + quad*8);
            bf16x8 b1f = ld8(VWTb + (16+l16)*VWST + c*32 + quad*8);
            o0 = MF(ap, b0, o0); o1 = MF(ap, b1f, o1);
            CBAR;
          }
          #pragma unroll
          for (int r=0;r<4;r++){
            int row = m16 + quad*4 + r;
            u16* x0 = Xb + row*XST + l16;
            u16* x1 = Xb + row*XST + 16 + l16;
            f32x2 xv = { bf2f(*x0), bf2f(*x1) };
            f32x2 iv = { inv[r], inv[r] };
            f32x2 ov = f32x2{o0[r], o1[r]} * iv + (xv + OB2);
            u32 pk = pk2bf(ov);
            *x0 = (u16)pk; *x1 = (u16)(pk>>16);
          }
        }
      }
    }
    __syncthreads();

    // ===== Phase D: LN2 stats =====
    ln_stats(Xb, MS, RS, tid);
    __syncthreads();

    // ===== Phase E: MLP, 64-hidden chunks, barrier-free (r8 exact) =====
    {
      f32x2 G2[4], B2[4];
      #pragma unroll
      for (int p=0;p<4;p++){
        G2[p] = f32x2{BIAS[160+quad*8+2*p], BIAS[160+quad*8+2*p+1]};
        B2[p] = f32x2{BIAS[192+quad*8+2*p], BIAS[192+quad*8+2*p+1]};
      }
      bf16x8 anc[4];
      #pragma unroll
      for (int t=0;t<4;t++){
        int m = w + 4*t;
        if (m < NMT) anc[t] = build_nfrag(Xb, MS, RS, m*16+l16, quad, G2, B2);
      }
      f32x4 oacc[4][2];
      #pragma unroll
      for (int t=0;t<4;t++){ oacc[t][0] = Z; oacc[t][1] = Z; }
      const char* w1f = wsl + 8*1024;
      const char* w2f = wsl + 40*1024;
      const float* BW1 = (const float*)((const char*)ws + WS_B1) + l*HIDN;

      for (int hc = 0; hc < HIDN; hc += 64){
        bf16x8 bw1[4], bw2[2][2];
        #pragma unroll
        for (int nt=0;nt<4;nt++)
          bw1[nt] = *(const bf16x8*)(w1f + (hc/16 + nt)*1024 + lane*16);
        #pragma unroll
        for (int kc=0;kc<2;kc++){
          bw2[kc][0] = *(const bf16x8*)(w2f + ((hc/32 + kc)*2    )*1024 + lane*16);
          bw2[kc][1] = *(const bf16x8*)(w2f + ((hc/32 + kc)*2 + 1)*1024 + lane*16);
        }
        f32x2 b1v2[4];
        #pragma unroll
        for (int nt=0;nt<4;nt++){
          float bb = BW1[hc + nt*16 + l16];
          b1v2[nt] = f32x2{bb, bb};
        }
        #pragma unroll
        for (int t=0;t<4;t++){
          int m = w + 4*t;
          if (m < NMT){
            #pragma unroll
            for (int nt=0;nt<4;nt++){
              f32x4 h = MF(anc[t], bw1[nt], Z);
              #pragma unroll
              for (int rp=0;rp<2;rp++){
                f32x2 z = f32x2{h[2*rp], h[2*rp+1]} + b1v2[nt];
                f32x2 a = z * nl2e2;
                f32x2 e = { __builtin_amdgcn_exp2f(a.x), __builtin_amdgcn_exp2f(a.y) };
                f32x2 d = one2 + e;
                f32x2 rc = { __builtin_amdgcn_rcpf(d.x), __builtin_amdgcn_rcpf(d.y) };
                f32x2 s = z * rc;
                u32 pk = pk2bf(s);
                qm[(quad*4+2*rp  )*MST + nt*16 + l16] = (u16)pk;
                qm[(quad*4+2*rp+1)*MST + nt*16 + l16] = (u16)(pk>>16);
              }
            }
            CBAR;
            bf16x8 ah0 = ld8(qm + l16*MST + quad*8);
            bf16x8 ah1 = ld8(qm + l16*MST + 32 + quad*8);
            oacc[t][0] = MF(ah0, bw2[0][0], oacc[t][0]);
            oacc[t][0] = MF(ah1, bw2[1][0], oacc[t][0]);
            oacc[t][1] = MF(ah0, bw2[0][1], oacc[t][1]);
            oacc[t][1] = MF(ah1, bw2[1][1], oacc[t][1]);
            CBAR;
          }
        }
      }

      f32x2 b2v2 = {BIAS[224+l16], BIAS[240+l16]};
      #pragma unroll
      for (int t=0;t<4;t++){
        int m = w + 4*t;
        if (m < NMT){
          int m16 = m*16;
          #pragma unroll
          for (int r=0;r<4;r++){
            int row = m16 + quad*4 + r;
            u16* x0 = Xb + row*XST + l16;
            u16* x1 = Xb + row*XST + 16 + l16;
            f32x2 xv = { bf2f(*x0), bf2f(*x1) };
            f32x2 ov = f32x2{oacc[t][0][r], oacc[t][1][r]} + (xv + b2v2);
            u32 pk = pk2bf(ov);
            *x0 = (u16)pk; *x1 = (u16)(pk>>16);
          }
        }
      }
    }
    __syncthreads();
  }

  // ===== final head =====
  const float* FW = (const float*)((const char*)ws + WS_FIN);
  if (tid < 32){
    BIAS[tid]    = FW[tid];
    BIAS[32+tid] = FW[32+tid];
    BIAS[64+tid] = FW[64+tid];
  }
  __syncthreads();
  float part = 0.f;
  if (tid < SS){
    const u32* row = (const u32*)(Xb + tid*XST);
    f32x2 v[16]; f32x2 s2 = {0.f,0.f};
    #pragma unroll
    for (int i=0;i<16;i++){ f32x2 p = upk2(row[i]); v[i] = p; s2 += p; }
    float m = (s2.x+s2.y) * (1.f/EE);
    f32x2 m2 = {m,m};
    f32x2 var2 = {0.f,0.f};
    #pragma unroll
    for (int i=0;i<16;i++){ f32x2 d = v[i]-m2; var2 += d*d; }
    float rs = rsqrtf((var2.x+var2.y)*(1.f/EE) + 1e-5f);
    f32x2 rs2 = {rs, rs};
    f32x2 dot2 = {0.f,0.f};
    #pragma unroll
    for (int i=0;i<16;i++){
      f32x2 g  = {BIAS[2*i], BIAS[2*i+1]};
      f32x2 bb = {BIAS[32+2*i], BIAS[33+2*i]};
      f32x2 wp = {BIAS[64+2*i], BIAS[65+2*i]};
      dot2 += ((v[i]-m2)*rs2*g + bb) * wp;
    }
    part = dot2.x + dot2.y + FW[96];
  }
  #pragma unroll
  for (int off=32; off; off>>=1) part += __shfl_xor(part, off);
  float* REDF = (float*)(smem + QS_OFF);
  __syncthreads();
  if (lane == 0) REDF[w] = part;
  __syncthreads();
  if (tid == 0){
    float u = REDF[0] + REDF[1] + REDF[2] + REDF[3];
    int ex = expid[b];
    float corr = FW[257+ex];
    #pragma unroll
    for (int c = 0; c < CWN; ++c){
      float pre = u * FW[97+c] + FW[113+c];
      pre = pre > 0.f ? pre : (__expf(pre) - 1.f);
      corr += pre * FW[129 + ex*CWN + c];
    }
    float res = corr + u;
    if (F32) ((float*)out)[b] = res;
    else     ((u16*)out)[b]  = f2bf(res);
  }
}

__global__ __launch_bounds__(256, 3) void tr_kernel(
    const int* __restrict__ seq, const int* __restrict__ expid,
    const void* __restrict__ tok_emb, const void* __restrict__ pos_emb,
    const void* __restrict__ ws, void* __restrict__ out)
{
  __shared__ __align__(16) unsigned char smem[SMEM_SZ];
  if (sniff_bf16(tok_emb, threadIdx.x))
    tr_body<false>(seq, expid, tok_emb, pos_emb, ws, out, smem);
  else
    tr_body<true >(seq, expid, tok_emb, pos_emb, ws, out, smem);
}

extern "C" void kernel_launch(void* const* d_in, const int* in_sizes, int n_in,
                              void* d_out, int out_size, void* d_ws, size_t ws_size,
                              hipStream_t stream)
{
  (void)in_sizes; (void)n_in; (void)ws_size; (void)out_size;
  const void* tok_emb = d_in[2];
  fmt_frags<<<dim3(288), dim3(64), 0, stream>>>(
      tok_emb, d_in[6], d_in[7], d_in[8], d_in[12], d_in[16], d_in[18], d_ws);
  fmt_bias<<<dim3(1), dim3(256), 0, stream>>>(
      tok_emb, d_in[9], d_in[10], d_in[11], d_in[12], d_in[13],
      d_in[4], d_in[5], d_in[14], d_in[15], d_in[17], d_in[19],
      d_in[20], d_in[21], d_in[22], d_in[23],
      d_in[24], d_in[25], d_in[26], d_in[27], d_ws);
  tr_kernel<<<dim3(BB), dim3(256), 0, stream>>>(
      (const int*)d_in[0], (const int*)d_in[1], tok_emb, d_in[3], d_ws, d_out);
}

// Round 12
// 923.438 us; speedup vs baseline: 1.3550x; 1.0788x over previous
//
#include <hip/hip_runtime.h>

// TrPredictor round 12 = r11 + Phase-C rewrite: S^T operand-swap attention.
// S^T = MF(K_frag, Q_frag) puts keys in C-layout quad*4 groups; P^T stays in
// registers as bf16x4 halves and feeds PV as a concatenated B-operand.
// No P LDS round trip (was 56 stores + 7 serialized store->load chains/tile).
// Phases A/B/D/E identical to r11 (996 us verified).

#define SS   201
#define SP   208
#define NMT  13
#define EE   32
#define HIDN 512
#define NTRL 4
#define CWN  16
#define BB   4096
#define XST  36
#define QST  36
#define MST  72
#define VWST 228

#define X_OFF    0
#define K_OFF    14976
#define VWT_OFF  29952   // VW^T [32][228]; MLP: 4x[16][72] scratch aliases (r8 layout)
#define QS_OFF   44544
#define MS_OFF   49152
#define RS_OFF   49984
#define BIAS_OFF 50816
#define SMEM_SZ  51840

#define WS_FRAG  0        // 288 tiles x 1024 B; per layer: 0,1=q 2,3=k 4,5=wvo 6,7=unused
#define WS_BIAS  294912
#define WS_B1    299008
#define WS_FIN   307200
#define L2E      1.4426950408889634f

typedef unsigned short u16;
typedef unsigned int   u32;
typedef short bf16x4 __attribute__((ext_vector_type(4)));
typedef short bf16x8 __attribute__((ext_vector_type(8)));
typedef float f32x4  __attribute__((ext_vector_type(4)));
typedef float f32x2  __attribute__((ext_vector_type(2)));

#define CBAR asm volatile("" ::: "memory")

__device__ __forceinline__ f32x4 MF(bf16x8 a, bf16x8 b, f32x4 c){
  return __builtin_amdgcn_mfma_f32_16x16x32_bf16(a, b, c, 0, 0, 0);
}
__device__ __forceinline__ float bf2f(u16 u){ return __uint_as_float(((u32)u)<<16); }
__device__ __forceinline__ u16 f2bf(float f){            // exact RNE (cold paths)
  u32 u = __float_as_uint(f);
  u += 0x7fffu + ((u>>16)&1u);
  return (u16)(u>>16);
}
__device__ __forceinline__ u16 f2bf_fast(float f){
  return (u16)((__float_as_uint(f) + 0x8000u) >> 16);
}
__device__ __forceinline__ u32 pk2bf(f32x2 v){
#if defined(__has_builtin) && __has_builtin(__builtin_amdgcn_cvt_pk_bf16_f32)
  auto r = __builtin_amdgcn_cvt_pk_bf16_f32(v.x, v.y);
  u32 u; __builtin_memcpy(&u, &r, 4); return u;
#else
  return ((__float_as_uint(v.x)+0x8000u)>>16) | ((__float_as_uint(v.y)+0x8000u) & 0xffff0000u);
#endif
}
__device__ __forceinline__ f32x2 upk2(u32 d){
  return f32x2{ __uint_as_float(d<<16), __uint_as_float(d & 0xffff0000u) };
}
template<bool F32>
__device__ __forceinline__ float ldv(const void* p, int i){
  if (F32) return ((const float*)p)[i];
  return bf2f(((const u16*)p)[i]);
}
template<bool F32>
__device__ __forceinline__ u16 ldbf(const void* p, int i){
  if (F32) return f2bf(((const float*)p)[i]);
  return ((const u16*)p)[i];
}
__device__ __forceinline__ bf16x8 ld8(const u16* p){
  const bf16x4* q = (const bf16x4*)p;
  bf16x4 lo = q[0], hi = q[1];
  bf16x8 r = {lo[0],lo[1],lo[2],lo[3],hi[0],hi[1],hi[2],hi[3]};
  return r;
}
__device__ __forceinline__ bf16x8 cat44(bf16x4 lo, bf16x4 hi){
  bf16x8 r = {lo[0],lo[1],lo[2],lo[3],hi[0],hi[1],hi[2],hi[3]};
  return r;
}
__device__ __forceinline__ bf16x8 mk8(u32 a0, u32 a1, u32 a2, u32 a3){
  u32 t[4] = {a0,a1,a2,a3};
  bf16x8 r; __builtin_memcpy(&r, t, 16); return r;
}

__device__ __forceinline__ int sniff_bf16(const void* tok_emb, int tid){
  int sane = 0;
  if (tid < 64){
    u16 wd = ((const u16*)tok_emb)[tid];
    int e = (wd >> 7) & 0xFF;
    sane = (e >= 100 && e <= 140) ? 1 : 0;
  }
  return (__syncthreads_count(sane) >= 52) ? 1 : 0;
}

// ===== pre-kernel 1: weight fragments (grid 288 x 64), r8 layout =====
template<bool F32>
__device__ __forceinline__ void frag_body(const void* wq, const void* wk,
    const void* wv, const void* wo, const void* w1, const void* w2, void* ws)
{
  int t = blockIdx.x;
  int l = t / 72, k = t % 72;
  int lane = threadIdx.x, l16 = lane & 15, quad = lane >> 4;
  bf16x8 v;
  if (k < 8){
    int mat = k >> 1, half = k & 1;
    if (mat == 2){
      // wvo = wv @ wo  (f32 accumulate, single bf16 rounding)
      int col = half*16 + l16;
      #pragma unroll
      for (int j=0;j<8;j++){
        int a = quad*8 + j;
        float acc = 0.f;
        for (int e=0;e<EE;e++)
          acc += ldv<F32>(wv, l*1024 + a*32 + e) * ldv<F32>(wo, l*1024 + e*32 + col);
        v[j] = (short)f2bf(acc);
      }
    } else {
      const void* src = (mat==0)? wq : (mat==1)? wk : wo;
      #pragma unroll
      for (int j=0;j<8;j++)
        v[j] = (short)ldbf<F32>(src, l*1024 + (quad*8+j)*32 + half*16 + l16);
    }
  } else if (k < 40){
    int nt = k - 8;
    #pragma unroll
    for (int j=0;j<8;j++)
      v[j] = (short)ldbf<F32>(w1, l*16384 + (quad*8+j)*512 + nt*16 + l16);
  } else {
    int kc = (k-40)>>1, nh = (k-40)&1;
    #pragma unroll
    for (int j=0;j<8;j++)
      v[j] = (short)ldbf<F32>(w2, l*16384 + (kc*32+quad*8+j)*32 + nh*16 + l16);
  }
  *(bf16x8*)((char*)ws + WS_FRAG + t*1024 + lane*16) = v;
}

__global__ __launch_bounds__(64) void fmt_frags(
    const void* __restrict__ tok_emb,
    const void* __restrict__ wq, const void* __restrict__ wk,
    const void* __restrict__ wv, const void* __restrict__ wo,
    const void* __restrict__ w1, const void* __restrict__ w2,
    void* __restrict__ ws)
{
  if (sniff_bf16(tok_emb, threadIdx.x)) frag_body<false>(wq,wk,wv,wo,w1,w2,ws);
  else                                  frag_body<true >(wq,wk,wv,wo,w1,w2,ws);
}

// ===== pre-kernel 2: biases / LN / head params =====
template<bool F32>
__device__ __forceinline__ void bias_body(
    const void* bq, const void* bk, const void* bv, const void* wo, const void* bo,
    const void* ln1_g, const void* ln1_b, const void* ln2_g, const void* ln2_b,
    const void* b1, const void* b2,
    const void* lnf_g, const void* lnf_b, const void* wpen, const void* bpen,
    const void* wfan, const void* bfan, const void* wcal, const void* bcal,
    void* ws)
{
  int tid = threadIdx.x, idx = tid & 31, grp = tid >> 5;
  float* BW  = (float*)((char*)ws + WS_BIAS);
  float* BW1 = (float*)((char*)ws + WS_B1);
  float* FW  = (float*)((char*)ws + WS_FIN);
  for (int l=0;l<NTRL;l++){
    float v = 0.f;
    switch(grp){
      case 0: v = ldv<F32>(bq, l*32+idx); break;
      case 1: v = ldv<F32>(bk, l*32+idx); break;
      case 2: {
        float acc = ldv<F32>(bo, l*32+idx);
        for (int e=0;e<EE;e++) acc += ldv<F32>(bv, l*32+e) * ldv<F32>(wo, l*1024 + e*32 + idx);
        v = acc; break;
      }
      case 3: v = ldv<F32>(ln1_g, l*32+idx); break;
      case 4: v = ldv<F32>(ln1_b, l*32+idx); break;
      case 5: v = ldv<F32>(ln2_g, l*32+idx); break;
      case 6: v = ldv<F32>(ln2_b, l*32+idx); break;
      case 7: v = ldv<F32>(b2,   l*32+idx); break;
    }
    BW[l*256 + tid] = v;
  }
  for (int i=tid; i<NTRL*HIDN; i+=256) BW1[i] = ldv<F32>(b1, i);
  if (tid < 32){
    FW[tid]    = ldv<F32>(lnf_g, tid);
    FW[32+tid] = ldv<F32>(lnf_b, tid);
    FW[64+tid] = ldv<F32>(wpen, tid);
  }
  if (tid == 0) FW[96] = ldv<F32>(bpen, 0);
  if (tid < 16){ FW[97+tid] = ldv<F32>(wfan, tid); FW[113+tid] = ldv<F32>(bfan, tid); }
  if (tid < 128) FW[129+tid] = ldv<F32>(wcal, tid);
  if (tid < 8)   FW[257+tid] = ldv<F32>(bcal, tid);
}

__global__ __launch_bounds__(256) void fmt_bias(
    const void* __restrict__ tok_emb,
    const void* __restrict__ bq, const void* __restrict__ bk,
    const void* __restrict__ bv, const void* __restrict__ wo, const void* __restrict__ bo,
    const void* __restrict__ ln1_g, const void* __restrict__ ln1_b,
    const void* __restrict__ ln2_g, const void* __restrict__ ln2_b,
    const void* __restrict__ b1, const void* __restrict__ b2,
    const void* __restrict__ lnf_g, const void* __restrict__ lnf_b,
    const void* __restrict__ wpen, const void* __restrict__ bpen,
    const void* __restrict__ wfan, const void* __restrict__ bfan,
    const void* __restrict__ wcal, const void* __restrict__ bcal,
    void* __restrict__ ws)
{
  if (sniff_bf16(tok_emb, threadIdx.x))
    bias_body<false>(bq,bk,bv,wo,bo,ln1_g,ln1_b,ln2_g,ln2_b,b1,b2,
                     lnf_g,lnf_b,wpen,bpen,wfan,bfan,wcal,bcal,ws);
  else
    bias_body<true >(bq,bk,bv,wo,bo,ln1_g,ln1_b,ln2_g,ln2_b,b1,b2,
                     lnf_g,lnf_b,wpen,bpen,wfan,bfan,wcal,bcal,ws);
}

// ===== main kernel =====
__device__ __forceinline__ void ln_stats(const u16* Xb, float* MS, float* RS, int tid){
  if (tid < SP){
    const u32* row = (const u32*)(Xb + tid*XST);
    f32x2 v[16]; f32x2 s2 = {0.f,0.f};
    #pragma unroll
    for (int i=0;i<16;i++){ f32x2 p = upk2(row[i]); v[i] = p; s2 += p; }
    float m = (s2.x + s2.y) * (1.f/EE);
    f32x2 m2 = {m, m};
    f32x2 var2 = {0.f,0.f};
    #pragma unroll
    for (int i=0;i<16;i++){ f32x2 d = v[i]-m2; var2 += d*d; }
    MS[tid] = m;
    RS[tid] = rsqrtf((var2.x+var2.y)*(1.f/EE) + 1e-5f);
  }
}

__device__ __forceinline__ bf16x8 build_nfrag(const u16* Xb, const float* MS, const float* RS,
                                              int row, int quad, const f32x2* G2, const f32x2* B2){
  const u32* raw = (const u32*)(Xb + row*XST + quad*8);
  f32x2 m2 = { MS[row], MS[row] };
  f32x2 rs2 = { RS[row], RS[row] };
  u32 o[4];
  #pragma unroll
  for (int p=0;p<4;p++){
    f32x2 x = upk2(raw[p]);
    o[p] = pk2bf((x - m2) * rs2 * G2[p] + B2[p]);
  }
  bf16x8 r; __builtin_memcpy(&r, o, 16);
  return r;
}

template<bool F32>
__device__ __forceinline__ void tr_body(
    const int* seq, const int* expid,
    const void* tok_emb, const void* pos_emb,
    const void* ws, void* out, unsigned char* smem)
{
  u16*   Xb   = (u16*)(smem + X_OFF);
  u16*   Kb   = (u16*)(smem + K_OFF);
  u16*   VWTb = (u16*)(smem + VWT_OFF);
  u16*   QSb  = (u16*)(smem + QS_OFF);
  float* MS   = (float*)(smem + MS_OFF);
  float* RS   = (float*)(smem + RS_OFF);
  float* BIAS = (float*)(smem + BIAS_OFF);

  const int tid  = threadIdx.x;
  const int lane = tid & 63, w = tid >> 6;
  const int l16  = lane & 15, quad = lane >> 4;
  const int b    = blockIdx.x;
  const f32x4 Z  = {0.f,0.f,0.f,0.f};
  u16* qs = QSb + w*576;
  u16* qm = (u16*)(smem + VWT_OFF) + w*1152;   // r8 MLP scratch layout

  // ---- embedding + positional (pad rows zeroed) ----
  {
    const int* srow = seq + b*SS;
    for (int i = tid; i < SP*EE; i += 256){
      int s = i >> 5, e = i & 31;
      float val = 0.f;
      if (s < SS){
        int tok = srow[s];
        val = ldv<F32>(tok_emb, tok*EE + e) + ldv<F32>(pos_emb, s*EE + e);
      }
      Xb[s*XST + e] = f2bf(val);
    }
  }
  __syncthreads();

  const float qce = 0.2550546813f;  // (1/sqrt(32)) * log2(e)
  const f32x2 qce2 = {qce, qce};
  const f32x2 one2 = {1.f, 1.f};
  const f32x2 nl2e2 = {-L2E, -L2E};

  for (int l = 0; l < NTRL; ++l){
    const char* wsl = (const char*)ws + WS_FRAG + l*73728;
    // ===== Phase A =====
    bf16x8 bwq0 = *(const bf16x8*)(wsl + 0*1024 + lane*16);
    bf16x8 bwq1 = *(const bf16x8*)(wsl + 1*1024 + lane*16);
    bf16x8 bwk0 = *(const bf16x8*)(wsl + 2*1024 + lane*16);
    bf16x8 bwk1 = *(const bf16x8*)(wsl + 3*1024 + lane*16);
    bf16x8 bwv0 = *(const bf16x8*)(wsl + 4*1024 + lane*16);  // wvo halves
    bf16x8 bwv1 = *(const bf16x8*)(wsl + 5*1024 + lane*16);
    {
      const float* BW = (const float*)((const char*)ws + WS_BIAS) + l*256;
      BIAS[tid] = BW[tid];
    }
    for (int i = tid; i < 32*16; i += 256)
      VWTb[(i>>4)*VWST + 208 + (i&15)] = 0;
    ln_stats(Xb, MS, RS, tid);
    __syncthreads();

    // ===== Phase B: K, VW (= N@wvo), Q-fragments (r11 exact) =====
    bf16x8 aq[4];
    {
      f32x2 G2[4], B2[4];
      #pragma unroll
      for (int p=0;p<4;p++){
        G2[p] = f32x2{BIAS[96+quad*8+2*p], BIAS[96+quad*8+2*p+1]};
        B2[p] = f32x2{BIAS[128+quad*8+2*p], BIAS[128+quad*8+2*p+1]};
      }
      f32x2 bqb2 = {BIAS[l16],    BIAS[16+l16]};
      f32x2 bkb2 = {BIAS[32+l16], BIAS[48+l16]};
      #pragma unroll
      for (int t=0;t<4;t++){
        int m = w + 4*t;
        if (m < NMT){
          int m16 = m*16;
          bf16x8 an = build_nfrag(Xb, MS, RS, m16+l16, quad, G2, B2);
          f32x4 ck0 = MF(an, bwk0, Z), ck1 = MF(an, bwk1, Z);
          #pragma unroll
          for (int r=0;r<4;r++){
            int row = m16 + quad*4 + r;
            u32 pk = pk2bf(f32x2{ck0[r], ck1[r]} + bkb2);
            Kb[row*XST + l16]      = (u16)pk;
            Kb[row*XST + 16 + l16] = (u16)(pk>>16);
          }
          f32x4 cw0 = MF(an, bwv0, Z), cw1 = MF(an, bwv1, Z);
          #pragma unroll
          for (int r=0;r<4;r++){
            u32 pk = pk2bf(f32x2{cw0[r], cw1[r]});
            VWTb[l16*VWST      + m16 + quad*4 + r] = (u16)pk;
            VWTb[(16+l16)*VWST + m16 + quad*4 + r] = (u16)(pk>>16);
          }
          f32x4 cq0 = MF(an, bwq0, Z), cq1 = MF(an, bwq1, Z);
          #pragma unroll
          for (int r=0;r<4;r++){
            u32 pk = pk2bf((f32x2{cq0[r], cq1[r]} + bqb2) * qce2);
            qs[(quad*4+r)*QST + l16]      = (u16)pk;
            qs[(quad*4+r)*QST + 16 + l16] = (u16)(pk>>16);
          }
          CBAR;
          aq[t] = ld8(qs + l16*QST + quad*8);
          CBAR;
        }
      }
    }
    __syncthreads();

    // ===== Phase C: attention via S^T (no P LDS round trip) =====
    {
      const u16* vbase0 = VWTb + l16*VWST;
      const u16* vbase1 = VWTb + (16+l16)*VWST;
      f32x4 ob0 = *(const f32x4*)(BIAS + 64 + quad*4);       // bv@wo+bo, e=quad*4..+3
      f32x4 ob1 = *(const f32x4*)(BIAS + 80 + quad*4);       // e=16+quad*4..+3
      #pragma unroll
      for (int t=0;t<4;t++){
        int m = w + 4*t;
        if (m < NMT){
          int m16 = m*16;
          // S^T tiles: rows = keys (quad*4+r), cols = queries (l16)
          u32 pbw[13][2];
          float part = 0.f;
          #pragma unroll
          for (int kt=0; kt<13; kt++){
            bf16x8 kb8 = ld8(Kb + (kt*16+l16)*XST + quad*8);
            f32x4 St = MF(kb8, aq[t], Z);      // K . Q^T = S^T
            float e0 = __builtin_amdgcn_exp2f(St[0]);
            float e1 = __builtin_amdgcn_exp2f(St[1]);
            float e2 = __builtin_amdgcn_exp2f(St[2]);
            float e3 = __builtin_amdgcn_exp2f(St[3]);
            if (kt == 12){                      // keys 201..207: local idx >= 9
              int kb = quad*4;
              if (kb+0 >= 9) e0 = 0.f;
              if (kb+1 >= 9) e1 = 0.f;
              if (kb+2 >= 9) e2 = 0.f;
              if (kb+3 >= 9) e3 = 0.f;
            }
            part += (e0+e1)+(e2+e3);
            pbw[kt][0] = pk2bf(f32x2{e0,e1});
            pbw[kt][1] = pk2bf(f32x2{e2,e3});
          }
          part += __shfl_xor(part, 16);
          part += __shfl_xor(part, 32);
          float inv = __builtin_amdgcn_rcpf(part);   // per query l16

          // PV: O^T = VW^T . P^T, keys paired 2 tiles per K=32 MFMA
          f32x4 o0 = Z, o1 = Z;
          #pragma unroll
          for (int c=0;c<6;c++){
            bf16x4 a0l = *(const bf16x4*)(vbase0 + c*32 + quad*4);
            bf16x4 a0h = *(const bf16x4*)(vbase0 + c*32 + 16 + quad*4);
            bf16x4 a1l = *(const bf16x4*)(vbase1 + c*32 + quad*4);
            bf16x4 a1h = *(const bf16x4*)(vbase1 + c*32 + 16 + quad*4);
            bf16x8 B8 = mk8(pbw[2*c][0], pbw[2*c][1], pbw[2*c+1][0], pbw[2*c+1][1]);
            o0 = MF(cat44(a0l, a0h), B8, o0);
            o1 = MF(cat44(a1l, a1h), B8, o1);
          }
          {
            // tail: tile 12 + zeroed pad (VWT cols 208.. are zeroed; B upper = 0)
            bf16x4 a0l = *(const bf16x4*)(vbase0 + 192 + quad*4);
            bf16x4 a0h = *(const bf16x4*)(vbase0 + 208 + quad*4);
            bf16x4 a1l = *(const bf16x4*)(vbase1 + 192 + quad*4);
            bf16x4 a1h = *(const bf16x4*)(vbase1 + 208 + quad*4);
            bf16x8 B8 = mk8(pbw[12][0], pbw[12][1], 0u, 0u);
            o0 = MF(cat44(a0l, a0h), B8, o0);
            o1 = MF(cat44(a1l, a1h), B8, o1);
          }

          // X[row=m16+l16][cols quad*4..+3 and 16+quad*4..+3] += inv*O^T + ob
          u32* xr = (u32*)(Xb + (m16+l16)*XST);
          {
            u32 d0 = xr[quad*2], d1 = xr[quad*2+1];
            f32x2 r01 = f32x2{o0[0],o0[1]} * inv + (upk2(d0) + f32x2{ob0[0],ob0[1]});
            f32x2 r23 = f32x2{o0[2],o0[3]} * inv + (upk2(d1) + f32x2{ob0[2],ob0[3]});
            xr[quad*2]   = pk2bf(r01);
            xr[quad*2+1] = pk2bf(r23);
            u32 d2 = xr[8+quad*2], d3 = xr[8+quad*2+1];
            f32x2 s01 = f32x2{o1[0],o1[1]} * inv + (upk2(d2) + f32x2{ob1[0],ob1[1]});
            f32x2 s23 = f32x2{o1[2],o1[3]} * inv + (upk2(d3) + f32x2{ob1[2],ob1[3]});
            xr[8+quad*2]   = pk2bf(s01);
            xr[8+quad*2+1] = pk2bf(s23);
          }
        }
      }
    }
    __syncthreads();

    // ===== Phase D: LN2 stats =====
    ln_stats(Xb, MS, RS, tid);
    __syncthreads();

    // ===== Phase E: MLP, 64-hidden chunks, barrier-free (r8 exact) =====
    {
      f32x2 G2[4], B2[4];
      #pragma unroll
      for (int p=0;p<4;p++){
        G2[p] = f32x2{BIAS[160+quad*8+2*p], BIAS[160+quad*8+2*p+1]};
        B2[p] = f32x2{BIAS[192+quad*8+2*p], BIAS[192+quad*8+2*p+1]};
      }
      bf16x8 anc[4];
      #pragma unroll
      for (int t=0;t<4;t++){
        int m = w + 4*t;
        if (m < NMT) anc[t] = build_nfrag(Xb, MS, RS, m*16+l16, quad, G2, B2);
      }
      f32x4 oacc[4][2];
      #pragma unroll
      for (int t=0;t<4;t++){ oacc[t][0] = Z; oacc[t][1] = Z; }
      const char* w1f = wsl + 8*1024;
      const char* w2f = wsl + 40*1024;
      const float* BW1 = (const float*)((const char*)ws + WS_B1) + l*HIDN;

      for (int hc = 0; hc < HIDN; hc += 64){
        bf16x8 bw1[4], bw2[2][2];
        #pragma unroll
        for (int nt=0;nt<4;nt++)
          bw1[nt] = *(const bf16x8*)(w1f + (hc/16 + nt)*1024 + lane*16);
        #pragma unroll
        for (int kc=0;kc<2;kc++){
          bw2[kc][0] = *(const bf16x8*)(w2f + ((hc/32 + kc)*2    )*1024 + lane*16);
          bw2[kc][1] = *(const bf16x8*)(w2f + ((hc/32 + kc)*2 + 1)*1024 + lane*16);
        }
        f32x2 b1v2[4];
        #pragma unroll
        for (int nt=0;nt<4;nt++){
          float bb = BW1[hc + nt*16 + l16];
          b1v2[nt] = f32x2{bb, bb};
        }
        #pragma unroll
        for (int t=0;t<4;t++){
          int m = w + 4*t;
          if (m < NMT){
            #pragma unroll
            for (int nt=0;nt<4;nt++){
              f32x4 h = MF(anc[t], bw1[nt], Z);
              #pragma unroll
              for (int rp=0;rp<2;rp++){
                f32x2 z = f32x2{h[2*rp], h[2*rp+1]} + b1v2[nt];
                f32x2 a = z * nl2e2;
                f32x2 e = { __builtin_amdgcn_exp2f(a.x), __builtin_amdgcn_exp2f(a.y) };
                f32x2 d = one2 + e;
                f32x2 rc = { __builtin_amdgcn_rcpf(d.x), __builtin_amdgcn_rcpf(d.y) };
                f32x2 s = z * rc;
                u32 pk = pk2bf(s);
                qm[(quad*4+2*rp  )*MST + nt*16 + l16] = (u16)pk;
                qm[(quad*4+2*rp+1)*MST + nt*16 + l16] = (u16)(pk>>16);
              }
            }
            CBAR;
            bf16x8 ah0 = ld8(qm + l16*MST + quad*8);
            bf16x8 ah1 = ld8(qm + l16*MST + 32 + quad*8);
            oacc[t][0] = MF(ah0, bw2[0][0], oacc[t][0]);
            oacc[t][0] = MF(ah1, bw2[1][0], oacc[t][0]);
            oacc[t][1] = MF(ah0, bw2[0][1], oacc[t][1]);
            oacc[t][1] = MF(ah1, bw2[1][1], oacc[t][1]);
            CBAR;
          }
        }
      }

      f32x2 b2v2 = {BIAS[224+l16], BIAS[240+l16]};
      #pragma unroll
      for (int t=0;t<4;t++){
        int m = w + 4*t;
        if (m < NMT){
          int m16 = m*16;
          #pragma unroll
          for (int r=0;r<4;r++){
            int row = m16 + quad*4 + r;
            u16* x0 = Xb + row*XST + l16;
            u16* x1 = Xb + row*XST + 16 + l16;
            f32x2 xv = { bf2f(*x0), bf2f(*x1) };
            f32x2 ov = f32x2{oacc[t][0][r], oacc[t][1][r]} + (xv + b2v2);
            u32 pk = pk2bf(ov);
            *x0 = (u16)pk; *x1 = (u16)(pk>>16);
          }
        }
      }
    }
    __syncthreads();
  }

  // ===== final head =====
  const float* FW = (const float*)((const char*)ws + WS_FIN);
  if (tid < 32){
    BIAS[tid]    = FW[tid];
    BIAS[32+tid] = FW[32+tid];
    BIAS[64+tid] = FW[64+tid];
  }
  __syncthreads();
  float part = 0.f;
  if (tid < SS){
    const u32* row = (const u32*)(Xb + tid*XST);
    f32x2 v[16]; f32x2 s2 = {0.f,0.f};
    #pragma unroll
    for (int i=0;i<16;i++){ f32x2 p = upk2(row[i]); v[i] = p; s2 += p; }
    float m = (s2.x+s2.y) * (1.f/EE);
    f32x2 m2 = {m,m};
    f32x2 var2 = {0.f,0.f};
    #pragma unroll
    for (int i=0;i<16;i++){ f32x2 d = v[i]-m2; var2 += d*d; }
    float rs = rsqrtf((var2.x+var2.y)*(1.f/EE) + 1e-5f);
    f32x2 rs2 = {rs, rs};
    f32x2 dot2 = {0.f,0.f};
    #pragma unroll
    for (int i=0;i<16;i++){
      f32x2 g  = {BIAS[2*i], BIAS[2*i+1]};
      f32x2 bb = {BIAS[32+2*i], BIAS[33+2*i]};
      f32x2 wp = {BIAS[64+2*i], BIAS[65+2*i]};
      dot2 += ((v[i]-m2)*rs2*g + bb) * wp;
    }
    part = dot2.x + dot2.y + FW[96];
  }
  #pragma unroll
  for (int off=32; off; off>>=1) part += __shfl_xor(part, off);
  float* REDF = (float*)(smem + QS_OFF);
  __syncthreads();
  if (lane == 0) REDF[w] = part;
  __syncthreads();
  if (tid == 0){
    float u = REDF[0] + REDF[1] + REDF[2] + REDF[3];
    int ex = expid[b];
    float corr = FW[257+ex];
    #pragma unroll
    for (int c = 0; c < CWN; ++c){
      float pre = u * FW[97+c] + FW[113+c];
      pre = pre > 0.f ? pre : (__expf(pre) - 1.f);
      corr += pre * FW[129 + ex*CWN + c];
    }
    float res = corr + u;
    if (F32) ((float*)out)[b] = res;
    else     ((u16*)out)[b]  = f2bf(res);
  }
}

__global__ __launch_bounds__(256, 3) void tr_kernel(
    const int* __restrict__ seq, const int* __restrict__ expid,
    const void* __restrict__ tok_emb, const void* __restrict__ pos_emb,
    const void* __restrict__ ws, void* __restrict__ out)
{
  __shared__ __align__(16) unsigned char smem[SMEM_SZ];
  if (sniff_bf16(tok_emb, threadIdx.x))
    tr_body<false>(seq, expid, tok_emb, pos_emb, ws, out, smem);
  else
    tr_body<true >(seq, expid, tok_emb, pos_emb, ws, out, smem);
}

extern "C" void kernel_launch(void* const* d_in, const int* in_sizes, int n_in,
                              void* d_out, int out_size, void* d_ws, size_t ws_size,
                              hipStream_t stream)
{
  (void)in_sizes; (void)n_in; (void)ws_size; (void)out_size;
  const void* tok_emb = d_in[2];
  fmt_frags<<<dim3(288), dim3(64), 0, stream>>>(
      tok_emb, d_in[6], d_in[7], d_in[8], d_in[12], d_in[16], d_in[18], d_ws);
  fmt_bias<<<dim3(1), dim3(256), 0, stream>>>(
      tok_emb, d_in[9], d_in[10], d_in[11], d_in[12], d_in[13],
      d_in[4], d_in[5], d_in[14], d_in[15], d_in[17], d_in[19],
      d_in[20], d_in[21], d_in[22], d_in[23],
      d_in[24], d_in[25], d_in[26], d_in[27], d_ws);
  tr_kernel<<<dim3(BB), dim3(256), 0, stream>>>(
      (const int*)d_in[0], (const int*)d_in[1], tok_emb, d_in[3], d_ws, d_out);
}